// Round 4
// baseline (329.553 us; speedup 1.0000x reference)
//
#include <hip/hip_runtime.h>
#include <hip/hip_bf16.h>
#include <stdint.h>

// x[4,2048,4096] f32, qweight[4096,4096] i32, scale/zp f32 scalars, bias[4096] f32
// out = x @ (scale*(q-zp))^T + bias : M=8192, N=4096, K=4096, f32 out.
#define M_DIM 8192
#define N_DIM 4096
#define K_DIM 4096

typedef __attribute__((ext_vector_type(8))) __bf16 bf16x8;
typedef __attribute__((ext_vector_type(4))) float f32x4;
typedef __attribute__((ext_vector_type(16))) float f32x16;
typedef __attribute__((ext_vector_type(8))) unsigned short ushort8;

__device__ __forceinline__ unsigned short f2bf(float f) {
  union { float f; uint32_t u; } v; v.f = f;
  uint32_t u = v.u;
  return (unsigned short)((u + 0x7FFFu + ((u >> 16) & 1u)) >> 16);  // RNE
}

__device__ __forceinline__ void gload_lds16(const void* g, void* l) {
  __builtin_amdgcn_global_load_lds((const __attribute__((address_space(1))) void*)g,
                                   (__attribute__((address_space(3))) void*)l,
                                   16, 0, 0);
}

#define RAW_BAR() asm volatile("s_barrier" ::: "memory")
#define VMW(n) asm volatile("s_waitcnt vmcnt(" #n ")" ::: "memory")
#define LGKM0()                                        \
  do {                                                 \
    asm volatile("s_waitcnt lgkmcnt(0)" ::: "memory"); \
    __builtin_amdgcn_sched_barrier(0);                 \
  } while (0)
#define NOOP do {} while (0)

// ---- prepack kernels ----
__global__ void cvt_x_kernel(const float* __restrict__ x, unsigned short* __restrict__ xb,
                             long long n8) {
  long long i = (long long)blockIdx.x * blockDim.x + threadIdx.x;
  long long stride = (long long)gridDim.x * blockDim.x;
  for (; i < n8; i += stride) {
    const float4* p = (const float4*)x + i * 2;
    float4 a = p[0], b = p[1];
    ushort8 u;
    u[0] = f2bf(a.x); u[1] = f2bf(a.y); u[2] = f2bf(a.z); u[3] = f2bf(a.w);
    u[4] = f2bf(b.x); u[5] = f2bf(b.y); u[6] = f2bf(b.z); u[7] = f2bf(b.w);
    *(ushort8*)(xb + i * 8) = u;
  }
}

__global__ void dequant_w_kernel(const int* __restrict__ q, const float* __restrict__ scale,
                                 const float* __restrict__ zp, unsigned short* __restrict__ wb,
                                 long long n8) {
  float s = scale[0], z = zp[0];
  long long i = (long long)blockIdx.x * blockDim.x + threadIdx.x;
  long long stride = (long long)gridDim.x * blockDim.x;
  for (; i < n8; i += stride) {
    const int4* p = (const int4*)q + i * 2;
    int4 a = p[0], b = p[1];
    ushort8 u;
    u[0] = f2bf(s * ((float)a.x - z)); u[1] = f2bf(s * ((float)a.y - z));
    u[2] = f2bf(s * ((float)a.z - z)); u[3] = f2bf(s * ((float)a.w - z));
    u[4] = f2bf(s * ((float)b.x - z)); u[5] = f2bf(s * ((float)b.y - z));
    u[6] = f2bf(s * ((float)b.z - z)); u[7] = f2bf(s * ((float)b.w - z));
    *(ushort8*)(wb + i * 8) = u;
  }
}

// ---- main GEMM: 256x256 tile, BK=32, 8 waves (2Mx4N), 4-deep LDS ring,
// mfma_f32_32x32x16_bf16 (4m x 2n frags/wave), counted vmcnt (T4),
// XOR granule swizzle both-sides (T2), 2 barriers/iter, setprio (T5).
#define BK 32
#define NT (K_DIM / BK)           // 128
#define BUF_SHORTS 16384          // per ring slot (A 8192 + B 8192 shorts)

__global__ __launch_bounds__(512, 2) void gemm256_kernel(
    const unsigned short* __restrict__ xb, const unsigned short* __restrict__ wb,
    const float* __restrict__ bias, float* __restrict__ out) {
  __shared__ unsigned short lds[4 * BUF_SHORTS];  // 128 KiB

  const int t = threadIdx.x;
  const int lane = t & 63;
  const int wid = t >> 6;          // 0..7
  const int wr = wid >> 2;         // 0..1  (M half)
  const int wc = wid & 3;          // 0..3  (N quarter)
  const int l31 = lane & 31;       // frag row/col
  const int lhi = lane >> 5;       // k half-block

  // XCD-aware bijective swizzle; grid = 512 (divisible by 8)
  const int bid = blockIdx.x;
  const int swz = ((bid & 7) << 6) | (bid >> 3);
  const int bx = swz & 15;         // N/256 = 16
  const int by = swz >> 4;         // M/256 = 32
  const int brow = by * 256, bcol = bx * 256;

  // staging: per tile, A = 256x32 bf16 = 16 KiB = 512 thr x 2 loads x 16B.
  // linear LDS dest; source granule pre-swizzled (involution matches read XOR):
  // LDS row r granule g holds global granule g ^ ((r>>1)&3).
  const int r2 = t >> 2;
  const int gG = (t & 3) ^ ((t >> 3) & 3);
  const unsigned short* gA = xb + (size_t)(brow + r2) * K_DIM + gG * 8;
  const unsigned short* gB = wb + (size_t)(bcol + r2) * K_DIM + gG * 8;

  // read-side swizzled granule offsets (in shorts) for k-step ks=0,1:
  // global granule = ks*2 + lhi; row low bits -> (l31>>1)&3
  const int xr = (l31 >> 1) & 3;
  const int g8_0 = ((0 * 2 + lhi) ^ xr) * 8;
  const int g8_1 = ((1 * 2 + lhi) ^ xr) * 8;

  // per-lane LDS row offsets (in shorts, x32 cols)
  int aoff[4], boff[2];
  #pragma unroll
  for (int m = 0; m < 4; ++m) aoff[m] = (wr * 128 + m * 32 + l31) * 32;
  #pragma unroll
  for (int n = 0; n < 2; ++n) boff[n] = (wc * 64 + n * 32 + l31) * 32;

  bf16x8 bfv[2][2];                 // [n][ks], persists PH_A -> PH_B
  f32x16 acc[4][2] = {};            // [m][n]

  #define STAGE_A(tile)                                                        \
    do {                                                                       \
      unsigned short* l_ = lds + ((tile) & 3) * BUF_SHORTS + t * 8;            \
      const unsigned short* g_ = gA + (size_t)(tile) * BK;                     \
      gload_lds16(g_, l_);                                                     \
      gload_lds16(g_ + (size_t)128 * K_DIM, l_ + 4096);                        \
    } while (0)

  #define STAGE_B(tile)                                                        \
    do {                                                                       \
      unsigned short* l_ = lds + ((tile) & 3) * BUF_SHORTS + 8192 + t * 8;     \
      const unsigned short* g_ = gB + (size_t)(tile) * BK;                     \
      gload_lds16(g_, l_);                                                     \
      gload_lds16(g_ + (size_t)128 * K_DIM, l_ + 4096);                        \
    } while (0)

  // Phase A (no barriers): reads af[0..1][*] + all bfv (8 x b128), MFMA m=0,1.
  #define PH_A(tile, STG)                                                      \
    do {                                                                       \
      const unsigned short* la_ = lds + ((tile) & 3) * BUF_SHORTS;             \
      const unsigned short* lb_ = la_ + 8192;                                  \
      bf16x8 af[2][2];                                                         \
      _Pragma("unroll")                                                        \
      for (int m = 0; m < 2; ++m) {                                            \
        af[m][0] = *(const bf16x8*)(la_ + aoff[m] + g8_0);                     \
        af[m][1] = *(const bf16x8*)(la_ + aoff[m] + g8_1);                     \
      }                                                                        \
      _Pragma("unroll")                                                        \
      for (int n = 0; n < 2; ++n) {                                            \
        bfv[n][0] = *(const bf16x8*)(lb_ + boff[n] + g8_0);                    \
        bfv[n][1] = *(const bf16x8*)(lb_ + boff[n] + g8_1);                    \
      }                                                                        \
      STG;                                                                     \
      LGKM0();                                                                 \
      __builtin_amdgcn_s_setprio(1);                                           \
      _Pragma("unroll")                                                        \
      for (int ks = 0; ks < 2; ++ks) {                                         \
        _Pragma("unroll")                                                      \
        for (int m = 0; m < 2; ++m) {                                          \
          _Pragma("unroll")                                                    \
          for (int n = 0; n < 2; ++n)                                          \
            acc[m][n] = __builtin_amdgcn_mfma_f32_32x32x16_bf16(               \
                af[m][ks], bfv[n][ks], acc[m][n], 0, 0, 0);                    \
        }                                                                      \
      }                                                                        \
      __builtin_amdgcn_s_setprio(0);                                           \
    } while (0)

  // Phase B: reads af[2..3][*] (4 x b128), MFMA m=2,3; carries the iter's
  // vmcnt + both barriers (these two barriers carry ALL cross-wave hazards).
  #define PH_B(tile, STG, WT)                                                  \
    do {                                                                       \
      const unsigned short* la_ = lds + ((tile) & 3) * BUF_SHORTS;             \
      bf16x8 af[2][2];                                                         \
      _Pragma("unroll")                                                        \
      for (int m = 0; m < 2; ++m) {                                            \
        af[m][0] = *(const bf16x8*)(la_ + aoff[2 + m] + g8_0);                 \
        af[m][1] = *(const bf16x8*)(la_ + aoff[2 + m] + g8_1);                 \
      }                                                                        \
      STG;                                                                     \
      WT;                                                                      \
      RAW_BAR();                                                               \
      LGKM0();                                                                 \
      __builtin_amdgcn_s_setprio(1);                                           \
      _Pragma("unroll")                                                        \
      for (int ks = 0; ks < 2; ++ks) {                                         \
        _Pragma("unroll")                                                      \
        for (int m = 0; m < 2; ++m) {                                          \
          _Pragma("unroll")                                                    \
          for (int n = 0; n < 2; ++n)                                          \
            acc[2 + m][n] = __builtin_amdgcn_mfma_f32_32x32x16_bf16(           \
                af[m][ks], bfv[n][ks], acc[2 + m][n], 0, 0, 0);                \
        }                                                                      \
      }                                                                        \
      __builtin_amdgcn_s_setprio(0);                                           \
      RAW_BAR();                                                               \
    } while (0)

  // prologue: 3 tiles (12 loads) in flight; retire tile 0 (VMW leaves 8).
  STAGE_A(0); STAGE_B(0);
  STAGE_A(1); STAGE_B(1);
  STAGE_A(2); STAGE_B(2);
  VMW(8);
  RAW_BAR();

  // steady state: VMW(8) at iter tt retires tile tt+1 (resident for iter tt+1
  // after PH_B's end barrier); slot (tt+3)&3 == (tt-1)&3 is safe to overwrite
  // because all waves' tile-(tt-1) ds_reads completed before each wave's
  // PH_B(tt-1) lgkmcnt(0), which precedes the end barrier every stage follows.
  for (int tt = 0; tt < NT - 3; ++tt) {
    PH_A(tt, STAGE_A(tt + 3));
    PH_B(tt, STAGE_B(tt + 3), VMW(8));
  }
  PH_A(NT - 3, NOOP); PH_B(NT - 3, NOOP, VMW(4));
  PH_A(NT - 2, NOOP); PH_B(NT - 2, NOOP, VMW(0));
  PH_A(NT - 1, NOOP); PH_B(NT - 1, NOOP, NOOP);

  #undef STAGE_A
  #undef STAGE_B
  #undef PH_A
  #undef PH_B

  // epilogue: 32x32 C/D layout col = lane&31, row = (reg&3)+8*(reg>>2)+4*(lane>>5)
  #pragma unroll
  for (int n = 0; n < 2; ++n) {
    const int col = bcol + wc * 64 + n * 32 + l31;
    const float bv = bias[col];
    #pragma unroll
    for (int m = 0; m < 4; ++m) {
      const int rbase = brow + wr * 128 + m * 32 + 4 * lhi;
      #pragma unroll
      for (int r = 0; r < 16; ++r) {
        const int row = rbase + (r & 3) + 8 * (r >> 2);
        out[(size_t)row * N_DIM + col] = acc[m][n][r] + bv;
      }
    }
  }
}

// ---- fallback (ws too small): fused dequant 128^2 tile, correct but slower ----
__global__ __launch_bounds__(256) void gemm_fallback_kernel(
    const float* __restrict__ x, const int* __restrict__ qw,
    const float* __restrict__ scale, const float* __restrict__ zp,
    const float* __restrict__ bias, float* __restrict__ out) {
  __shared__ unsigned short lds_a[128 * 32];
  __shared__ unsigned short lds_b[128 * 32];
  const int t = threadIdx.x;
  const int lane = t & 63;
  const int wid = t >> 6;
  const int wr = wid >> 1, wc = wid & 1;
  const int fr = lane & 15, fq = lane >> 4;
  const int nwg = gridDim.x;
  const int cpx = nwg >> 3;
  const int bid = blockIdx.x;
  const int swz = (bid & 7) * cpx + (bid >> 3);
  const int bx = swz & 31, by = swz >> 5;
  const int brow = by * 128, bcol = bx * 128;
  const int r0 = t >> 2, c8 = (t & 3) * 8;
  f32x4 acc[4][4] = {};
  const float ss = scale[0], zs = zp[0];
  for (int kk = 0; kk < K_DIM; kk += 32) {
    ushort8 ua[2], ub[2];
    #pragma unroll
    for (int i = 0; i < 2; ++i) {
      const float* gp = x + (size_t)(brow + i * 64 + r0) * K_DIM + kk + c8;
      float4 v0 = *(const float4*)gp;
      float4 v1 = *(const float4*)(gp + 4);
      ua[i][0] = f2bf(v0.x); ua[i][1] = f2bf(v0.y); ua[i][2] = f2bf(v0.z); ua[i][3] = f2bf(v0.w);
      ua[i][4] = f2bf(v1.x); ua[i][5] = f2bf(v1.y); ua[i][6] = f2bf(v1.z); ua[i][7] = f2bf(v1.w);
      const int* qp = qw + (size_t)(bcol + i * 64 + r0) * K_DIM + kk + c8;
      int4 q0 = *(const int4*)qp;
      int4 q1 = *(const int4*)(qp + 4);
      ub[i][0] = f2bf(ss * ((float)q0.x - zs)); ub[i][1] = f2bf(ss * ((float)q0.y - zs));
      ub[i][2] = f2bf(ss * ((float)q0.z - zs)); ub[i][3] = f2bf(ss * ((float)q0.w - zs));
      ub[i][4] = f2bf(ss * ((float)q1.x - zs)); ub[i][5] = f2bf(ss * ((float)q1.y - zs));
      ub[i][6] = f2bf(ss * ((float)q1.z - zs)); ub[i][7] = f2bf(ss * ((float)q1.w - zs));
    }
    __syncthreads();
    #pragma unroll
    for (int i = 0; i < 2; ++i) {
      *(ushort8*)(lds_a + ((size_t)i * 256 + t) * 8) = ua[i];
      *(ushort8*)(lds_b + ((size_t)i * 256 + t) * 8) = ub[i];
    }
    __syncthreads();
    bf16x8 af[4], bfr[4];
    #pragma unroll
    for (int m = 0; m < 4; ++m)
      af[m] = *(const bf16x8*)(lds_a + (wr * 64 + m * 16 + fr) * 32 + fq * 8);
    #pragma unroll
    for (int n = 0; n < 4; ++n)
      bfr[n] = *(const bf16x8*)(lds_b + (wc * 64 + n * 16 + fr) * 32 + fq * 8);
    #pragma unroll
    for (int m = 0; m < 4; ++m)
      #pragma unroll
      for (int n = 0; n < 4; ++n)
        acc[m][n] = __builtin_amdgcn_mfma_f32_16x16x32_bf16(af[m], bfr[n], acc[m][n], 0, 0, 0);
  }
  #pragma unroll
  for (int n = 0; n < 4; ++n) {
    const int col = bcol + wc * 64 + n * 16 + fr;
    const float bv = bias[col];
    #pragma unroll
    for (int m = 0; m < 4; ++m) {
      const int rowb = brow + wr * 64 + m * 16 + fq * 4;
      #pragma unroll
      for (int j = 0; j < 4; ++j)
        out[(size_t)(rowb + j) * N_DIM + col] = acc[m][n][j] + bv;
    }
  }
}

extern "C" void kernel_launch(void* const* d_in, const int* in_sizes, int n_in,
                              void* d_out, int out_size, void* d_ws, size_t ws_size,
                              hipStream_t stream) {
  const float* x = (const float*)d_in[0];
  const int* qw = (const int*)d_in[1];
  const float* scale = (const float*)d_in[2];
  const float* zp = (const float*)d_in[3];
  const float* bias = (const float*)d_in[4];
  float* out = (float*)d_out;

  const size_t xb_bytes = (size_t)M_DIM * K_DIM * 2;
  const size_t wb_bytes = (size_t)N_DIM * K_DIM * 2;

  if (ws_size >= xb_bytes + wb_bytes) {
    unsigned short* xbuf = (unsigned short*)d_ws;
    unsigned short* wbuf = (unsigned short*)((char*)d_ws + xb_bytes);
    cvt_x_kernel<<<2048, 256, 0, stream>>>(x, xbuf, (long long)M_DIM * K_DIM / 8);
    dequant_w_kernel<<<2048, 256, 0, stream>>>(qw, scale, zp, wbuf, (long long)N_DIM * K_DIM / 8);
    const int grid = (M_DIM / 256) * (N_DIM / 256);  // 512, divisible by 8
    gemm256_kernel<<<grid, 512, 0, stream>>>(xbuf, wbuf, bias, out);
  } else {
    const int grid = (M_DIM / 128) * (N_DIM / 128);  // 2048
    gemm_fallback_kernel<<<grid, 256, 0, stream>>>(x, qw, scale, zp, bias, out);
  }
}

// Round 5
// 281.872 us; speedup vs baseline: 1.1692x; 1.1692x over previous
//
#include <hip/hip_runtime.h>
#include <hip/hip_bf16.h>
#include <stdint.h>

// x[4,2048,4096] f32, qweight[4096,4096] i32, scale/zp f32 scalars, bias[4096] f32
// out = x @ (scale*(q-zp))^T + bias : M=8192, N=4096, K=4096, f32 out.
#define M_DIM 8192
#define N_DIM 4096
#define K_DIM 4096

typedef __attribute__((ext_vector_type(8))) __bf16 bf16x8;
typedef __attribute__((ext_vector_type(4))) float f32x4;
typedef __attribute__((ext_vector_type(8))) unsigned short ushort8;

__device__ __forceinline__ unsigned short f2bf(float f) {
  union { float f; uint32_t u; } v; v.f = f;
  uint32_t u = v.u;
  return (unsigned short)((u + 0x7FFFu + ((u >> 16) & 1u)) >> 16);  // RNE
}

__device__ __forceinline__ void gload_lds16(const void* g, void* l) {
  __builtin_amdgcn_global_load_lds((const __attribute__((address_space(1))) void*)g,
                                   (__attribute__((address_space(3))) void*)l,
                                   16, 0, 0);
}

#define RAW_BAR() asm volatile("s_barrier" ::: "memory")
#define VMW(n) asm volatile("s_waitcnt vmcnt(" #n ")" ::: "memory")
#define LGKM0()                                        \
  do {                                                 \
    asm volatile("s_waitcnt lgkmcnt(0)" ::: "memory"); \
    __builtin_amdgcn_sched_barrier(0);                 \
  } while (0)
#define NOOP do {} while (0)

// ---- prepack kernels ----
__global__ void cvt_x_kernel(const float* __restrict__ x, unsigned short* __restrict__ xb,
                             long long n8) {
  long long i = (long long)blockIdx.x * blockDim.x + threadIdx.x;
  long long stride = (long long)gridDim.x * blockDim.x;
  for (; i < n8; i += stride) {
    const float4* p = (const float4*)x + i * 2;
    float4 a = p[0], b = p[1];
    ushort8 u;
    u[0] = f2bf(a.x); u[1] = f2bf(a.y); u[2] = f2bf(a.z); u[3] = f2bf(a.w);
    u[4] = f2bf(b.x); u[5] = f2bf(b.y); u[6] = f2bf(b.z); u[7] = f2bf(b.w);
    *(ushort8*)(xb + i * 8) = u;
  }
}

__global__ void dequant_w_kernel(const int* __restrict__ q, const float* __restrict__ scale,
                                 const float* __restrict__ zp, unsigned short* __restrict__ wb,
                                 long long n8) {
  float s = scale[0], z = zp[0];
  long long i = (long long)blockIdx.x * blockDim.x + threadIdx.x;
  long long stride = (long long)gridDim.x * blockDim.x;
  for (; i < n8; i += stride) {
    const int4* p = (const int4*)q + i * 2;
    int4 a = p[0], b = p[1];
    ushort8 u;
    u[0] = f2bf(s * ((float)a.x - z)); u[1] = f2bf(s * ((float)a.y - z));
    u[2] = f2bf(s * ((float)a.z - z)); u[3] = f2bf(s * ((float)a.w - z));
    u[4] = f2bf(s * ((float)b.x - z)); u[5] = f2bf(s * ((float)b.y - z));
    u[6] = f2bf(s * ((float)b.z - z)); u[7] = f2bf(s * ((float)b.w - z));
    *(ushort8*)(wb + i * 8) = u;
  }
}

// ---- main GEMM: m201-style 8-phase template.
// 256x256 tile, BK=64, 8 waves (2Mx4N, 128x64/wave), 16x16x32 MFMA.
// LDS: 2 dbuf x (A[256][64] + B[256][64]) bf16 = 128 KiB. Tile T lives in dbuf T&1.
// Per K-tile: 4 quadrant phases {ds_read subtile, stage 1 half-tile, [waits],
// barrier, lgkmcnt(0), setprio(1), 16 MFMA, setprio(0), barrier}.
// Stage order per 8 phases: A0(T1) A1(T1) B0(T0+2) B1(T0+2) A0(T0+2) A1(T0+2)
// B0(T1+2) B1(T1+2); VMW(4) only at phases 4 and 8 (T4: never drain to 0).
// Swizzle: LDS row r granule g holds global granule g^(r&7); reads XOR back.
#define NT2 (K_DIM / 64)          // 64 K-tiles
#define DBUF_SHORTS 32768         // A 16384 + B 16384 shorts per dbuf

__global__ __launch_bounds__(512, 2) void gemm256_kernel(
    const unsigned short* __restrict__ xb, const unsigned short* __restrict__ wb,
    const float* __restrict__ bias, float* __restrict__ out) {
  __shared__ unsigned short lds[2 * DBUF_SHORTS];  // 128 KiB

  const int t = threadIdx.x;
  const int lane = t & 63;
  const int wid = t >> 6;          // 0..7
  const int wr = wid >> 2;         // 0..1  (M half)
  const int wc = wid & 3;          // 0..3  (N quarter)
  const int fr = lane & 15, fq = lane >> 4;
  const int fr7 = fr & 7;

  // XCD-aware bijective swizzle; grid = 512 (divisible by 8)
  const int bid = blockIdx.x;
  const int swz = ((bid & 7) << 6) | (bid >> 3);
  const int bx = swz & 15;         // N/256 = 16
  const int by = swz >> 4;         // M/256 = 32
  const int brow = by * 256, bcol = bx * 256;

  // staging: half-tile = 128 rows x 64 k = 16 KiB = 512 thr x 2 gload16.
  // thread t, load l: row = (t>>3) + 64*l (+128*half), LDS granule = t&7,
  // sourcing global granule (t&7)^((t>>3)&7) (row&7-invariant across l, half).
  const int gsrc = (t & 7) ^ ((t >> 3) & 7);
  const unsigned short* gAs = xb + (size_t)(brow + (t >> 3)) * K_DIM + gsrc * 8;
  const unsigned short* gBs = wb + (size_t)(bcol + (t >> 3)) * K_DIM + gsrc * 8;

  // read-side: frag (row, ks) reads LDS granule (ks*4+fq)^(row&7); row&7 = fr&7.
  const int gs0 = (fq ^ fr7) * 8;
  const int gs1 = ((4 | fq) ^ fr7) * 8;
  const int aoff = (wr * 128 + fr) * 64;          // + m*1024 (+ d*DBUF_SHORTS)
  const int boff = 16384 + (wc * 64 + fr) * 64;   // + n*1024

  bf16x8 af[8][2], bfv[4][2];
  f32x4 acc[8][4] = {};

  #define STG(isB, h, tile)                                                    \
    do {                                                                       \
      unsigned short* l_ = lds + ((tile) & 1) * DBUF_SHORTS + (isB) * 16384 +  \
                           (h) * 8192 + t * 8;                                 \
      const unsigned short* g_ = ((isB) ? gBs : gAs) +                         \
                                 (size_t)(h) * 128 * K_DIM + (size_t)(tile) * 64; \
      gload_lds16(g_, l_);                                                     \
      gload_lds16(g_ + (size_t)64 * K_DIM, l_ + 4096);                         \
    } while (0)

  #define RD_A(d, m)                                                           \
    af[m][0] = *(const bf16x8*)(lds + (d) * DBUF_SHORTS + aoff + (m) * 1024 + gs0); \
    af[m][1] = *(const bf16x8*)(lds + (d) * DBUF_SHORTS + aoff + (m) * 1024 + gs1);
  #define RD_B(d, n)                                                           \
    bfv[n][0] = *(const bf16x8*)(lds + (d) * DBUF_SHORTS + boff + (n) * 1024 + gs0); \
    bfv[n][1] = *(const bf16x8*)(lds + (d) * DBUF_SHORTS + boff + (n) * 1024 + gs1);

  #define MMQ(MS, NS)                                                          \
    __builtin_amdgcn_s_setprio(1);                                             \
    _Pragma("unroll")                                                          \
    for (int ks = 0; ks < 2; ++ks) {                                           \
      _Pragma("unroll")                                                        \
      for (int m = 0; m < 4; ++m) {                                            \
        _Pragma("unroll")                                                      \
        for (int n = 0; n < 2; ++n)                                            \
          acc[MS + m][NS + n] = __builtin_amdgcn_mfma_f32_16x16x32_bf16(       \
              af[MS + m][ks], bfv[NS + n][ks], acc[MS + m][NS + n], 0, 0, 0);  \
      }                                                                        \
    }                                                                          \
    __builtin_amdgcn_s_setprio(0);

  // Phases. Stage expr passed as __VA_ARGS__ (contains commas).
  #define PH1(d, ...)                                                          \
    RD_A(d, 0) RD_A(d, 1) RD_A(d, 2) RD_A(d, 3) RD_B(d, 0) RD_B(d, 1)          \
    __VA_ARGS__;                                                               \
    asm volatile("s_waitcnt lgkmcnt(8)" ::: "memory");                         \
    RAW_BAR(); LGKM0(); MMQ(0, 0) RAW_BAR();
  #define PH2(d, ...)                                                          \
    RD_B(d, 2) RD_B(d, 3)                                                      \
    __VA_ARGS__;                                                               \
    RAW_BAR(); LGKM0(); MMQ(0, 2) RAW_BAR();
  #define PH3(d, ...)                                                          \
    RD_A(d, 4) RD_A(d, 5) RD_A(d, 6) RD_A(d, 7)                                \
    __VA_ARGS__;                                                               \
    RAW_BAR(); LGKM0(); MMQ(4, 0) RAW_BAR();
  #define PH4(wt, ...)                                                         \
    __VA_ARGS__;                                                               \
    wt;                                                                        \
    RAW_BAR(); MMQ(4, 2) RAW_BAR();

  // prologue: B0(0) B1(0) A0(0) A1(0) B0(1) B1(1) = 12 loads; retire tile 0.
  STG(1, 0, 0); STG(1, 1, 0); STG(0, 0, 0); STG(0, 1, 0);
  STG(1, 0, 1); STG(1, 1, 1);
  VMW(4);
  RAW_BAR();

  // steady: iter i computes tiles T0=2i (buf0, ph1-4) and T1=2i+1 (buf1, ph5-8).
  // VMW(4)@ph4 retires tile T1 (needed ph5); VMW(4)@ph8 retires T0+2 (next ph1).
  // Every stage targets a region whose last reader drained >=1 barrier earlier.
  for (int i = 0; i < NT2 / 2 - 1; ++i) {
    const int T1 = 2 * i + 1;
    PH1(0, STG(0, 0, T1))
    PH2(0, STG(0, 1, T1))
    PH3(0, STG(1, 0, T1 + 1))
    PH4(VMW(4), STG(1, 1, T1 + 1))
    PH1(1, STG(0, 0, T1 + 1))
    PH2(1, STG(0, 1, T1 + 1))
    PH3(1, STG(1, 0, T1 + 2))
    PH4(VMW(4), STG(1, 1, T1 + 2))
  }
  // last iter: tiles 62 (buf0), 63 (buf1); only A0/A1(63) remain to stage.
  PH1(0, STG(0, 0, NT2 - 1))
  PH2(0, STG(0, 1, NT2 - 1))
  PH3(0, NOOP)
  PH4(VMW(0), NOOP)
  PH1(1, NOOP)
  PH2(1, NOOP)
  PH3(1, NOOP)
  PH4(NOOP, NOOP)

  #undef STG
  #undef RD_A
  #undef RD_B
  #undef MMQ
  #undef PH1
  #undef PH2
  #undef PH3
  #undef PH4

  // epilogue: C/D layout col = lane&15, row = (lane>>4)*4 + j
  #pragma unroll
  for (int n = 0; n < 4; ++n) {
    const int col = bcol + wc * 64 + n * 16 + fr;
    const float bv = bias[col];
    #pragma unroll
    for (int m = 0; m < 8; ++m) {
      const int rowb = brow + wr * 128 + m * 16 + fq * 4;
      #pragma unroll
      for (int j = 0; j < 4; ++j)
        out[(size_t)(rowb + j) * N_DIM + col] = acc[m][n][j] + bv;
    }
  }
}

// ---- fallback (ws too small): fused dequant 128^2 tile, correct but slower ----
__global__ __launch_bounds__(256) void gemm_fallback_kernel(
    const float* __restrict__ x, const int* __restrict__ qw,
    const float* __restrict__ scale, const float* __restrict__ zp,
    const float* __restrict__ bias, float* __restrict__ out) {
  __shared__ unsigned short lds_a[128 * 32];
  __shared__ unsigned short lds_b[128 * 32];
  const int t = threadIdx.x;
  const int lane = t & 63;
  const int wid = t >> 6;
  const int wr = wid >> 1, wc = wid & 1;
  const int fr = lane & 15, fq = lane >> 4;
  const int nwg = gridDim.x;
  const int cpx = nwg >> 3;
  const int bid = blockIdx.x;
  const int swz = (bid & 7) * cpx + (bid >> 3);
  const int bx = swz & 31, by = swz >> 5;
  const int brow = by * 128, bcol = bx * 128;
  const int r0 = t >> 2, c8 = (t & 3) * 8;
  f32x4 acc[4][4] = {};
  const float ss = scale[0], zs = zp[0];
  for (int kk = 0; kk < K_DIM; kk += 32) {
    ushort8 ua[2], ub[2];
    #pragma unroll
    for (int i = 0; i < 2; ++i) {
      const float* gp = x + (size_t)(brow + i * 64 + r0) * K_DIM + kk + c8;
      float4 v0 = *(const float4*)gp;
      float4 v1 = *(const float4*)(gp + 4);
      ua[i][0] = f2bf(v0.x); ua[i][1] = f2bf(v0.y); ua[i][2] = f2bf(v0.z); ua[i][3] = f2bf(v0.w);
      ua[i][4] = f2bf(v1.x); ua[i][5] = f2bf(v1.y); ua[i][6] = f2bf(v1.z); ua[i][7] = f2bf(v1.w);
      const int* qp = qw + (size_t)(bcol + i * 64 + r0) * K_DIM + kk + c8;
      int4 q0 = *(const int4*)qp;
      int4 q1 = *(const int4*)(qp + 4);
      ub[i][0] = f2bf(ss * ((float)q0.x - zs)); ub[i][1] = f2bf(ss * ((float)q0.y - zs));
      ub[i][2] = f2bf(ss * ((float)q0.z - zs)); ub[i][3] = f2bf(ss * ((float)q0.w - zs));
      ub[i][4] = f2bf(ss * ((float)q1.x - zs)); ub[i][5] = f2bf(ss * ((float)q1.y - zs));
      ub[i][6] = f2bf(ss * ((float)q1.z - zs)); ub[i][7] = f2bf(ss * ((float)q1.w - zs));
    }
    __syncthreads();
    #pragma unroll
    for (int i = 0; i < 2; ++i) {
      *(ushort8*)(lds_a + ((size_t)i * 256 + t) * 8) = ua[i];
      *(ushort8*)(lds_b + ((size_t)i * 256 + t) * 8) = ub[i];
    }
    __syncthreads();
    bf16x8 af[4], bfr[4];
    #pragma unroll
    for (int m = 0; m < 4; ++m)
      af[m] = *(const bf16x8*)(lds_a + (wr * 64 + m * 16 + fr) * 32 + fq * 8);
    #pragma unroll
    for (int n = 0; n < 4; ++n)
      bfr[n] = *(const bf16x8*)(lds_b + (wc * 64 + n * 16 + fr) * 32 + fq * 8);
    #pragma unroll
    for (int m = 0; m < 4; ++m)
      #pragma unroll
      for (int n = 0; n < 4; ++n)
        acc[m][n] = __builtin_amdgcn_mfma_f32_16x16x32_bf16(af[m], bfr[n], acc[m][n], 0, 0, 0);
  }
  #pragma unroll
  for (int n = 0; n < 4; ++n) {
    const int col = bcol + wc * 64 + n * 16 + fr;
    const float bv = bias[col];
    #pragma unroll
    for (int m = 0; m < 4; ++m) {
      const int rowb = brow + wr * 64 + m * 16 + fq * 4;
      #pragma unroll
      for (int j = 0; j < 4; ++j)
        out[(size_t)(rowb + j) * N_DIM + col] = acc[m][n][j] + bv;
    }
  }
}

extern "C" void kernel_launch(void* const* d_in, const int* in_sizes, int n_in,
                              void* d_out, int out_size, void* d_ws, size_t ws_size,
                              hipStream_t stream) {
  const float* x = (const float*)d_in[0];
  const int* qw = (const int*)d_in[1];
  const float* scale = (const float*)d_in[2];
  const float* zp = (const float*)d_in[3];
  const float* bias = (const float*)d_in[4];
  float* out = (float*)d_out;

  const size_t xb_bytes = (size_t)M_DIM * K_DIM * 2;
  const size_t wb_bytes = (size_t)N_DIM * K_DIM * 2;

  if (ws_size >= xb_bytes + wb_bytes) {
    unsigned short* xbuf = (unsigned short*)d_ws;
    unsigned short* wbuf = (unsigned short*)((char*)d_ws + xb_bytes);
    cvt_x_kernel<<<2048, 256, 0, stream>>>(x, xbuf, (long long)M_DIM * K_DIM / 8);
    dequant_w_kernel<<<2048, 256, 0, stream>>>(qw, scale, zp, wbuf, (long long)N_DIM * K_DIM / 8);
    const int grid = (M_DIM / 256) * (N_DIM / 256);  // 512, divisible by 8
    gemm256_kernel<<<grid, 512, 0, stream>>>(xbuf, wbuf, bias, out);
  } else {
    const int grid = (M_DIM / 128) * (N_DIM / 128);  // 2048
    gemm_fallback_kernel<<<grid, 256, 0, stream>>>(x, qw, scale, zp, bias, out);
  }
}